// Round 1
// baseline (537.243 us; speedup 1.0000x reference)
//
#include <hip/hip_runtime.h>
#include <hip/hip_bf16.h>

#define N_NODES 100000
#define N_EDGES 3200000
#define DDIM    256
#define M_PAD   100096   // 782 * 128
#define NBKT    782      // buckets = dst >> 7 (128 dsts per bucket)
#define BCAP    4608     // mean 4096 + 8 sigma
#define EPB_A   4096     // edges per binA block

typedef __attribute__((ext_vector_type(8))) short short8;
typedef __attribute__((ext_vector_type(4))) float f32x4;

typedef const __attribute__((address_space(1))) void gvoid_t;
typedef __attribute__((address_space(3))) void lvoid_t;

__device__ __forceinline__ void load_lds16(const void* g, void* l) {
  __builtin_amdgcn_global_load_lds((gvoid_t*)g, (lvoid_t*)l, 16, 0, 0);
}

__device__ __forceinline__ unsigned short f2bf(float f) {
  __hip_bfloat16 h = __float2bfloat16(f);
  return *(unsigned short*)&h;
}
__device__ __forceinline__ float bflo(unsigned u) { return __uint_as_float(u << 16); }
__device__ __forceinline__ float bfhi(unsigned u) { return __uint_as_float(u & 0xffff0000u); }

// ---------------- convert X (fp32 -> bf16), 4 elems/thread ----------------
__global__ void conv_x_kernel(const float* __restrict__ x, unsigned short* __restrict__ xb) {
  size_t i = (size_t)blockIdx.x * blockDim.x + threadIdx.x;
  size_t idx = i * 4;
  if (idx >= (size_t)N_NODES * DDIM) return;
  float4 v = *(const float4*)(x + idx);
  ushort4 o;
  o.x = f2bf(v.x); o.y = f2bf(v.y); o.z = f2bf(v.z); o.w = f2bf(v.w);
  *(ushort4*)(xb + idx) = o;
}

// ------------- convert W (fp32 [K][N] -> bf16 transposed [N][K]) ----------
__global__ void conv_w_kernel(const float* __restrict__ w, unsigned short* __restrict__ wt) {
  int t = blockIdx.x * blockDim.x + threadIdx.x;   // 65536 threads
  int n = t >> 8, k = t & 255;
  wt[t] = f2bf(w[k * 256 + n]);                    // wt[n*256 + k]
}

// ---------------- MFMA GEMM: support = Xb @ Wt^T  (bf16 out) --------------
__global__ __launch_bounds__(256) void gemm_kernel(const unsigned short* __restrict__ xb,
                                                   const unsigned short* __restrict__ wt,
                                                   unsigned short* __restrict__ sup) {
  __shared__ unsigned short As[128 * 32];
  __shared__ unsigned short Bs[128 * 32];
  const int tid  = threadIdx.x;
  const int w    = tid >> 6;
  const int lane = tid & 63;
  const int quad = lane >> 4;
  const int l15  = lane & 15;
  const int wr   = w >> 1, wc = w & 1;
  const int m0 = blockIdx.x * 128;
  const int n0 = blockIdx.y * 128;

  f32x4 acc[4][4] = {};

  const int srow   = lane >> 2;
  const int schunk = (lane & 3) * 8;

  for (int kt = 0; kt < 256; kt += 32) {
#pragma unroll
    for (int i = 0; i < 2; ++i) {
      int r = w * 32 + i * 16 + srow;
      load_lds16(xb + ((size_t)(m0 + r) * 256 + kt + schunk),
                 As + (w * 32 + i * 16) * 32);
      load_lds16(wt + ((size_t)(n0 + r) * 256 + kt + schunk),
                 Bs + (w * 32 + i * 16) * 32);
    }
    __syncthreads();

    short8 a[4], b[4];
#pragma unroll
    for (int mi = 0; mi < 4; ++mi)
      a[mi] = *(const short8*)(As + (wr * 64 + mi * 16 + l15) * 32 + quad * 8);
#pragma unroll
    for (int ni = 0; ni < 4; ++ni)
      b[ni] = *(const short8*)(Bs + (wc * 64 + ni * 16 + l15) * 32 + quad * 8);

#pragma unroll
    for (int mi = 0; mi < 4; ++mi)
#pragma unroll
      for (int ni = 0; ni < 4; ++ni)
        acc[mi][ni] = __builtin_amdgcn_mfma_f32_16x16x32_bf16(a[mi], b[ni], acc[mi][ni], 0, 0, 0);
    __syncthreads();
  }

#pragma unroll
  for (int mi = 0; mi < 4; ++mi) {
#pragma unroll
    for (int r = 0; r < 4; ++r) {
      size_t row = (size_t)(m0 + wr * 64 + mi * 16 + quad * 4 + r);
#pragma unroll
      for (int ni = 0; ni < 4; ++ni) {
        int col = n0 + wc * 64 + ni * 16 + l15;
        sup[row * 256 + col] = f2bf(acc[mi][ni][r]);
      }
    }
  }
}

// ---- pass A: bin edges into 782 fixed-capacity bucket regions (coalesced) ----
// pack: [w:32][dstlow:7 @bit17][src:17]
__global__ __launch_bounds__(256) void binA_kernel(const int* __restrict__ src,
                                                   const int* __restrict__ dst,
                                                   const float* __restrict__ wgt,
                                                   int* __restrict__ gcur,
                                                   unsigned long long* __restrict__ region) {
  __shared__ unsigned long long staged[EPB_A];
  __shared__ unsigned short sbkt[EPB_A];
  __shared__ int lhist[NBKT];
  __shared__ int lstart[NBKT];
  __shared__ int lcur[NBKT];
  __shared__ int gb[NBKT];
  __shared__ int csum[256];

  const int t = threadIdx.x;
  const int e0 = blockIdx.x * EPB_A;
  const int ecnt = min(EPB_A, N_EDGES - e0);

  for (int i = t; i < NBKT; i += 256) lhist[i] = 0;
  __syncthreads();
  for (int k = t; k < ecnt; k += 256)
    atomicAdd(&lhist[dst[e0 + k] >> 7], 1);
  __syncthreads();

  // blocked exclusive scan of lhist -> lstart (thread t owns [4t, 4t+4))
  int i0 = 4 * t;
  int a0 = (i0 + 0 < NBKT) ? lhist[i0 + 0] : 0;
  int a1 = (i0 + 1 < NBKT) ? lhist[i0 + 1] : 0;
  int a2 = (i0 + 2 < NBKT) ? lhist[i0 + 2] : 0;
  int a3 = (i0 + 3 < NBKT) ? lhist[i0 + 3] : 0;
  int s = a0 + a1 + a2 + a3;
  csum[t] = s;
  __syncthreads();
  for (int off = 1; off < 256; off <<= 1) {
    int v = (t >= off) ? csum[t - off] : 0;
    __syncthreads();
    csum[t] += v;
    __syncthreads();
  }
  int base = csum[t] - s;
  if (i0 + 0 < NBKT) lstart[i0 + 0] = base; base += a0;
  if (i0 + 1 < NBKT) lstart[i0 + 1] = base; base += a1;
  if (i0 + 2 < NBKT) lstart[i0 + 2] = base; base += a2;
  if (i0 + 3 < NBKT) lstart[i0 + 3] = base;
  __syncthreads();

  for (int i = t; i < NBKT; i += 256) {
    int c = lhist[i];
    int off = c ? atomicAdd(&gcur[i], c) : 0;
    gb[i] = i * BCAP + off;
    lcur[i] = lstart[i];
  }
  __syncthreads();

  for (int k = t; k < ecnt; k += 256) {
    int d  = dst[e0 + k];
    int sr = src[e0 + k];
    float w = wgt[e0 + k];
    int b = d >> 7;
    int p = atomicAdd(&lcur[b], 1);
    staged[p] = ((unsigned long long)__float_as_uint(w) << 32) |
                ((unsigned)(d & 127) << 17) | (unsigned)sr;
    sbkt[p] = (unsigned short)b;
  }
  __syncthreads();

  for (int j = t; j < ecnt; j += 256) {
    int b = sbkt[j];
    int addr = gb[b] + (j - lstart[b]);
    if (addr < (b + 1) * BCAP) region[addr] = staged[j];  // overflow guard (never fires)
  }
}

// ---- pass B: per-bucket in-place counting sort by local dst + rowse ----
__global__ __launch_bounds__(256) void csrB_kernel(unsigned long long* __restrict__ region,
                                                   const int* __restrict__ gcur,
                                                   int2* __restrict__ rowse) {
  __shared__ unsigned long long lcsr[BCAP];
  __shared__ int lhist[128], loff[128], lcur[128];
  const int t = threadIdx.x;
  const int b = blockIdx.x;
  const int cnt = min(gcur[b], BCAP);
  const int base = b * BCAP;

  if (t < 128) lhist[t] = 0;
  __syncthreads();
  for (int j = t; j < cnt; j += 256) {
    unsigned lo = (unsigned)(region[base + j] & 0xffffffffu);
    atomicAdd(&lhist[(lo >> 17) & 127], 1);
  }
  __syncthreads();
  if (t < 128) loff[t] = lhist[t];
  __syncthreads();
  for (int off = 1; off < 128; off <<= 1) {
    int v = (t >= off && t < 128) ? loff[t - off] : 0;
    __syncthreads();
    if (t < 128) loff[t] += v;
    __syncthreads();
  }
  if (t < 128) { loff[t] -= lhist[t]; lcur[t] = loff[t]; }
  __syncthreads();
  for (int j = t; j < cnt; j += 256) {
    unsigned long long e = region[base + j];
    int dl = (int)((e >> 17) & 127);
    int p = atomicAdd(&lcur[dl], 1);
    lcsr[p] = e;
  }
  __syncthreads();
  for (int j = t; j < cnt; j += 256) region[base + j] = lcsr[j];  // in-place sorted
  if (t < 128) {
    int gd = b * 128 + t;
    if (gd < N_NODES) rowse[gd] = make_int2(base + loff[t], base + lcur[t]);
  }
}

// ---------------- gather: 1 wave per node, lane owns 4 cols ---------------
// Unroll-8: keep 8 sup-row loads (4 KB/wave) in flight to break the
// outstanding-bytes (Little's-law) limit of the old unroll-2 body.
__global__ __launch_bounds__(64) void gather_kernel(const unsigned long long* __restrict__ packed,
                                                    const int2* __restrict__ rowse,
                                                    const unsigned short* __restrict__ sup,
                                                    const float* __restrict__ bias,
                                                    float* __restrict__ out) {
  int n = blockIdx.x;
  int l = threadIdx.x;
  int c0 = l * 4;
  int2 se = rowse[n];
  int start = se.x, end = se.y;
  float4 bv = *(const float4*)(bias + c0);
  float a0 = bv.x, a1 = bv.y, a2 = bv.z, a3 = bv.w;

  int i = start;
  // main loop: full unroll-8 blocks, no predication
  for (; i + 8 <= end; i += 8) {
    unsigned long long m[8];
#pragma unroll
    for (int k = 0; k < 8; ++k) m[k] = packed[i + k];
    uint2 p[8];
#pragma unroll
    for (int k = 0; k < 8; ++k)
      p[k] = *(const uint2*)(sup + (size_t)(m[k] & 0x1ffffu) * 256 + c0);
#pragma unroll
    for (int k = 0; k < 8; ++k) {
      float w = __uint_as_float((unsigned)(m[k] >> 32));
      a0 = fmaf(w, bflo(p[k].x), a0);
      a1 = fmaf(w, bfhi(p[k].x), a1);
      a2 = fmaf(w, bflo(p[k].y), a2);
      a3 = fmaf(w, bfhi(p[k].y), a3);
    }
  }
  // tail: one clamped/predicated unroll-8 block (keeps MLP; clamped lanes
  // re-read packed[start]'s row with weight forced to +0.0f -> L1 hit, no-op)
  if (i < end) {
    unsigned long long m[8];
#pragma unroll
    for (int k = 0; k < 8; ++k) {
      int j = i + k;
      unsigned long long mm = packed[j < end ? j : start];
      if (j >= end) mm &= 0x00000000ffffffffull;   // weight := +0.0f
      m[k] = mm;
    }
    uint2 p[8];
#pragma unroll
    for (int k = 0; k < 8; ++k)
      p[k] = *(const uint2*)(sup + (size_t)(m[k] & 0x1ffffu) * 256 + c0);
#pragma unroll
    for (int k = 0; k < 8; ++k) {
      float w = __uint_as_float((unsigned)(m[k] >> 32));
      a0 = fmaf(w, bflo(p[k].x), a0);
      a1 = fmaf(w, bfhi(p[k].x), a1);
      a2 = fmaf(w, bflo(p[k].y), a2);
      a3 = fmaf(w, bfhi(p[k].y), a3);
    }
  }
  *(float4*)(out + (size_t)n * 256 + c0) = make_float4(a0, a1, a2, a3);
}

extern "C" void kernel_launch(void* const* d_in, const int* in_sizes, int n_in,
                              void* d_out, int out_size, void* d_ws, size_t ws_size,
                              hipStream_t stream) {
  const float* x        = (const float*)d_in[0];
  const int*   edge_src = (const int*)d_in[1];
  const int*   edge_dst = (const int*)d_in[2];
  const float* edge_w   = (const float*)d_in[3];
  const float* weight   = (const float*)d_in[4];
  const float* bias     = (const float*)d_in[5];
  float* out = (float*)d_out;

  char* ws = (char*)d_ws;
  size_t off = 0;
  auto alloc = [&](size_t bytes) -> void* {
    void* p = ws + off;
    off = (off + bytes + 255) & ~(size_t)255;
    return p;
  };

  unsigned short* xb  = (unsigned short*)alloc((size_t)M_PAD * 256 * 2);  // 51.25 MB
  unsigned short* wt  = (unsigned short*)alloc(256 * 256 * 2);
  unsigned short* sup = (unsigned short*)alloc((size_t)M_PAD * 256 * 2);  // 51.25 MB

  // region/gcur/rowse alias xb (dead after gemm); region = 782*4608*8 = 28.84 MB
  char* xbb = (char*)xb;
  unsigned long long* region = (unsigned long long*)xbb;
  int*  gcur  = (int*)(xbb + (29u << 20));
  int2* rowse = (int2*)(xbb + (30u << 20));

  conv_x_kernel<<<25000, 256, 0, stream>>>(x, xb);
  conv_w_kernel<<<256, 256, 0, stream>>>(weight, wt);
  gemm_kernel<<<dim3(782, 2), 256, 0, stream>>>(xb, wt, sup);
  hipMemsetAsync(gcur, 0, NBKT * 4, stream);          // after gemm: gcur aliases xb
  binA_kernel<<<(N_EDGES + EPB_A - 1) / EPB_A, 256, 0, stream>>>(edge_src, edge_dst, edge_w,
                                                                 gcur, region);
  csrB_kernel<<<NBKT, 256, 0, stream>>>(region, gcur, rowse);
  gather_kernel<<<N_NODES, 64, 0, stream>>>(region, rowse, sup, bias, out);
}

// Round 2
// 531.095 us; speedup vs baseline: 1.0116x; 1.0116x over previous
//
#include <hip/hip_runtime.h>
#include <hip/hip_bf16.h>

#define N_NODES 100000
#define N_EDGES 3200000
#define DDIM    256
#define M_PAD   100096   // 782 * 128
#define NBKT    782      // buckets = dst >> 7 (128 dsts per bucket)
#define BCAP    4608     // mean 4096 + 8 sigma
#define EPB_A   4096     // edges per binA block
#define GT      512      // threads in fused csr+gather kernel

typedef __attribute__((ext_vector_type(8))) short short8;
typedef __attribute__((ext_vector_type(4))) float f32x4;

typedef const __attribute__((address_space(1))) void gvoid_t;
typedef __attribute__((address_space(3))) void lvoid_t;

__device__ __forceinline__ void load_lds16(const void* g, void* l) {
  __builtin_amdgcn_global_load_lds((gvoid_t*)g, (lvoid_t*)l, 16, 0, 0);
}

__device__ __forceinline__ unsigned short f2bf(float f) {
  __hip_bfloat16 h = __float2bfloat16(f);
  return *(unsigned short*)&h;
}
__device__ __forceinline__ float bflo(unsigned u) { return __uint_as_float(u << 16); }
__device__ __forceinline__ float bfhi(unsigned u) { return __uint_as_float(u & 0xffff0000u); }

// ---------------- convert X (fp32 -> bf16), 4 elems/thread ----------------
__global__ void conv_x_kernel(const float* __restrict__ x, unsigned short* __restrict__ xb) {
  size_t i = (size_t)blockIdx.x * blockDim.x + threadIdx.x;
  size_t idx = i * 4;
  if (idx >= (size_t)N_NODES * DDIM) return;
  float4 v = *(const float4*)(x + idx);
  ushort4 o;
  o.x = f2bf(v.x); o.y = f2bf(v.y); o.z = f2bf(v.z); o.w = f2bf(v.w);
  *(ushort4*)(xb + idx) = o;
}

// ------------- convert W (fp32 [K][N] -> bf16 transposed [N][K]) ----------
__global__ void conv_w_kernel(const float* __restrict__ w, unsigned short* __restrict__ wt) {
  int t = blockIdx.x * blockDim.x + threadIdx.x;   // 65536 threads
  int n = t >> 8, k = t & 255;
  wt[t] = f2bf(w[k * 256 + n]);                    // wt[n*256 + k]
}

// ---------------- MFMA GEMM: support = Xb @ Wt^T  (bf16 out) --------------
__global__ __launch_bounds__(256) void gemm_kernel(const unsigned short* __restrict__ xb,
                                                   const unsigned short* __restrict__ wt,
                                                   unsigned short* __restrict__ sup) {
  __shared__ unsigned short As[128 * 32];
  __shared__ unsigned short Bs[128 * 32];
  const int tid  = threadIdx.x;
  const int w    = tid >> 6;
  const int lane = tid & 63;
  const int quad = lane >> 4;
  const int l15  = lane & 15;
  const int wr   = w >> 1, wc = w & 1;
  const int m0 = blockIdx.x * 128;
  const int n0 = blockIdx.y * 128;

  f32x4 acc[4][4] = {};

  const int srow   = lane >> 2;
  const int schunk = (lane & 3) * 8;

  for (int kt = 0; kt < 256; kt += 32) {
#pragma unroll
    for (int i = 0; i < 2; ++i) {
      int r = w * 32 + i * 16 + srow;
      load_lds16(xb + ((size_t)(m0 + r) * 256 + kt + schunk),
                 As + (w * 32 + i * 16) * 32);
      load_lds16(wt + ((size_t)(n0 + r) * 256 + kt + schunk),
                 Bs + (w * 32 + i * 16) * 32);
    }
    __syncthreads();

    short8 a[4], b[4];
#pragma unroll
    for (int mi = 0; mi < 4; ++mi)
      a[mi] = *(const short8*)(As + (wr * 64 + mi * 16 + l15) * 32 + quad * 8);
#pragma unroll
    for (int ni = 0; ni < 4; ++ni)
      b[ni] = *(const short8*)(Bs + (wc * 64 + ni * 16 + l15) * 32 + quad * 8);

#pragma unroll
    for (int mi = 0; mi < 4; ++mi)
#pragma unroll
      for (int ni = 0; ni < 4; ++ni)
        acc[mi][ni] = __builtin_amdgcn_mfma_f32_16x16x32_bf16(a[mi], b[ni], acc[mi][ni], 0, 0, 0);
    __syncthreads();
  }

#pragma unroll
  for (int mi = 0; mi < 4; ++mi) {
#pragma unroll
    for (int r = 0; r < 4; ++r) {
      size_t row = (size_t)(m0 + wr * 64 + mi * 16 + quad * 4 + r);
#pragma unroll
      for (int ni = 0; ni < 4; ++ni) {
        int col = n0 + wc * 64 + ni * 16 + l15;
        sup[row * 256 + col] = f2bf(acc[mi][ni][r]);
      }
    }
  }
}

// ---- pass A: bin edges into 782 fixed-capacity bucket regions (coalesced) ----
// pack: [w:32][dstlow:7 @bit17][src:17]
__global__ __launch_bounds__(256) void binA_kernel(const int* __restrict__ src,
                                                   const int* __restrict__ dst,
                                                   const float* __restrict__ wgt,
                                                   int* __restrict__ gcur,
                                                   unsigned long long* __restrict__ region) {
  __shared__ unsigned long long staged[EPB_A];
  __shared__ unsigned short sbkt[EPB_A];
  __shared__ int lhist[NBKT];
  __shared__ int lstart[NBKT];
  __shared__ int lcur[NBKT];
  __shared__ int gb[NBKT];
  __shared__ int csum[256];

  const int t = threadIdx.x;
  const int e0 = blockIdx.x * EPB_A;
  const int ecnt = min(EPB_A, N_EDGES - e0);

  for (int i = t; i < NBKT; i += 256) lhist[i] = 0;
  __syncthreads();
  for (int k = t; k < ecnt; k += 256)
    atomicAdd(&lhist[dst[e0 + k] >> 7], 1);
  __syncthreads();

  // blocked exclusive scan of lhist -> lstart (thread t owns [4t, 4t+4))
  int i0 = 4 * t;
  int a0 = (i0 + 0 < NBKT) ? lhist[i0 + 0] : 0;
  int a1 = (i0 + 1 < NBKT) ? lhist[i0 + 1] : 0;
  int a2 = (i0 + 2 < NBKT) ? lhist[i0 + 2] : 0;
  int a3 = (i0 + 3 < NBKT) ? lhist[i0 + 3] : 0;
  int s = a0 + a1 + a2 + a3;
  csum[t] = s;
  __syncthreads();
  for (int off = 1; off < 256; off <<= 1) {
    int v = (t >= off) ? csum[t - off] : 0;
    __syncthreads();
    csum[t] += v;
    __syncthreads();
  }
  int base = csum[t] - s;
  if (i0 + 0 < NBKT) lstart[i0 + 0] = base; base += a0;
  if (i0 + 1 < NBKT) lstart[i0 + 1] = base; base += a1;
  if (i0 + 2 < NBKT) lstart[i0 + 2] = base; base += a2;
  if (i0 + 3 < NBKT) lstart[i0 + 3] = base;
  __syncthreads();

  for (int i = t; i < NBKT; i += 256) {
    int c = lhist[i];
    int off = c ? atomicAdd(&gcur[i], c) : 0;
    gb[i] = i * BCAP + off;
    lcur[i] = lstart[i];
  }
  __syncthreads();

  for (int k = t; k < ecnt; k += 256) {
    int d  = dst[e0 + k];
    int sr = src[e0 + k];
    float w = wgt[e0 + k];
    int b = d >> 7;
    int p = atomicAdd(&lcur[b], 1);
    staged[p] = ((unsigned long long)__float_as_uint(w) << 32) |
                ((unsigned)(d & 127) << 17) | (unsigned)sr;
    sbkt[p] = (unsigned short)b;
  }
  __syncthreads();

  for (int j = t; j < ecnt; j += 256) {
    int b = sbkt[j];
    int addr = gb[b] + (j - lstart[b]);
    if (addr < (b + 1) * BCAP) region[addr] = staged[j];  // overflow guard (never fires)
  }
}

// ---- fused pass B + gather: per-bucket counting sort in LDS, then gather
// straight from the LDS-sorted edge list (no region write-back, no re-read).
// 512 threads = 8 waves; wave w gathers dsts dl = w, w+8, ..., w+120.
// LDS ~38.4 KB -> 4 blocks/CU -> 32 waves/CU; all 782 blocks co-resident.
__global__ __launch_bounds__(GT) void csr_gather_kernel(
    const unsigned long long* __restrict__ region,
    const int* __restrict__ gcur,
    const unsigned short* __restrict__ sup,
    const float* __restrict__ bias,
    float* __restrict__ out) {
  __shared__ unsigned long long lcsr[BCAP];
  __shared__ int lhist[128], loff[128], lcur[128];
  const int t = threadIdx.x;
  const int b = blockIdx.x;
  const int cnt = min(gcur[b], BCAP);
  const int base = b * BCAP;

  // --- counting sort by local dst into lcsr ---
  if (t < 128) lhist[t] = 0;
  __syncthreads();
  for (int j = t; j < cnt; j += GT) {
    unsigned lo = (unsigned)(region[base + j] & 0xffffffffu);
    atomicAdd(&lhist[(lo >> 17) & 127], 1);
  }
  __syncthreads();
  if (t < 128) loff[t] = lhist[t];
  __syncthreads();
  for (int off = 1; off < 128; off <<= 1) {
    int v = (t >= off && t < 128) ? loff[t - off] : 0;
    __syncthreads();
    if (t < 128) loff[t] += v;
    __syncthreads();
  }
  if (t < 128) { loff[t] -= lhist[t]; lcur[t] = loff[t]; }
  __syncthreads();
  for (int j = t; j < cnt; j += GT) {
    unsigned long long e = region[base + j];
    int dl = (int)((e >> 17) & 127);
    int p = atomicAdd(&lcur[dl], 1);
    lcsr[p] = e;
  }
  __syncthreads();

  // --- gather: edge records broadcast from LDS, sup rows from global ---
  const int wv = t >> 6;
  const int c0 = (t & 63) * 4;
  float4 bv = *(const float4*)(bias + c0);

  for (int dl = wv; dl < 128; dl += 8) {
    int node = b * 128 + dl;
    if (node >= N_NODES) continue;   // wave-uniform
    int start = loff[dl];
    int end   = lcur[dl];
    float a0 = bv.x, a1 = bv.y, a2 = bv.z, a3 = bv.w;

    int i = start;
    for (; i + 2 <= end; i += 2) {
      unsigned long long m0 = lcsr[i];
      unsigned long long m1 = lcsr[i + 1];
      int   s0 = (int)(m0 & 0x1ffffu);
      float w0 = __uint_as_float((unsigned)(m0 >> 32));
      int   s1 = (int)(m1 & 0x1ffffu);
      float w1 = __uint_as_float((unsigned)(m1 >> 32));
      uint2 p0 = *(const uint2*)(sup + (size_t)s0 * 256 + c0);
      uint2 p1 = *(const uint2*)(sup + (size_t)s1 * 256 + c0);
      a0 = fmaf(w0, bflo(p0.x), a0);
      a1 = fmaf(w0, bfhi(p0.x), a1);
      a2 = fmaf(w0, bflo(p0.y), a2);
      a3 = fmaf(w0, bfhi(p0.y), a3);
      a0 = fmaf(w1, bflo(p1.x), a0);
      a1 = fmaf(w1, bfhi(p1.x), a1);
      a2 = fmaf(w1, bflo(p1.y), a2);
      a3 = fmaf(w1, bfhi(p1.y), a3);
    }
    if (i < end) {
      unsigned long long m0 = lcsr[i];
      int   s0 = (int)(m0 & 0x1ffffu);
      float w0 = __uint_as_float((unsigned)(m0 >> 32));
      uint2 p0 = *(const uint2*)(sup + (size_t)s0 * 256 + c0);
      a0 = fmaf(w0, bflo(p0.x), a0);
      a1 = fmaf(w0, bfhi(p0.x), a1);
      a2 = fmaf(w0, bflo(p0.y), a2);
      a3 = fmaf(w0, bfhi(p0.y), a3);
    }
    *(float4*)(out + (size_t)node * 256 + c0) = make_float4(a0, a1, a2, a3);
  }
}

extern "C" void kernel_launch(void* const* d_in, const int* in_sizes, int n_in,
                              void* d_out, int out_size, void* d_ws, size_t ws_size,
                              hipStream_t stream) {
  const float* x        = (const float*)d_in[0];
  const int*   edge_src = (const int*)d_in[1];
  const int*   edge_dst = (const int*)d_in[2];
  const float* edge_w   = (const float*)d_in[3];
  const float* weight   = (const float*)d_in[4];
  const float* bias     = (const float*)d_in[5];
  float* out = (float*)d_out;

  char* ws = (char*)d_ws;
  size_t off = 0;
  auto alloc = [&](size_t bytes) -> void* {
    void* p = ws + off;
    off = (off + bytes + 255) & ~(size_t)255;
    return p;
  };

  unsigned short* xb  = (unsigned short*)alloc((size_t)M_PAD * 256 * 2);  // 51.25 MB
  unsigned short* wt  = (unsigned short*)alloc(256 * 256 * 2);
  unsigned short* sup = (unsigned short*)alloc((size_t)M_PAD * 256 * 2);  // 51.25 MB

  // region/gcur alias xb (dead after gemm); region = 782*4608*8 = 28.84 MB
  char* xbb = (char*)xb;
  unsigned long long* region = (unsigned long long*)xbb;
  int*  gcur  = (int*)(xbb + (29u << 20));

  conv_x_kernel<<<25000, 256, 0, stream>>>(x, xb);
  conv_w_kernel<<<256, 256, 0, stream>>>(weight, wt);
  gemm_kernel<<<dim3(782, 2), 256, 0, stream>>>(xb, wt, sup);
  hipMemsetAsync(gcur, 0, NBKT * 4, stream);          // after gemm: gcur aliases xb
  binA_kernel<<<(N_EDGES + EPB_A - 1) / EPB_A, 256, 0, stream>>>(edge_src, edge_dst, edge_w,
                                                                 gcur, region);
  csr_gather_kernel<<<NBKT, GT, 0, stream>>>(region, gcur, sup, bias, out);
}

// Round 3
// 507.313 us; speedup vs baseline: 1.0590x; 1.0469x over previous
//
#include <hip/hip_runtime.h>
#include <hip/hip_bf16.h>

#define N_NODES 100000
#define N_EDGES 3200000
#define DDIM    256
#define M_PAD   100096   // 782 * 128
#define NBKT    782      // buckets = dst >> 7 (128 dsts per bucket)
#define BCAP    4608     // mean 4096 + 8 sigma
#define EPB_A   4096     // edges per binA block
#define GCAP    2432     // half-bucket capacity: mean 2048 + 8.5 sigma

// prep_kernel grid layout: [0,782) binA | [782,1038) conv_w | [1038,13538) conv_x
#define PREP_CONVW_BASE 782
#define PREP_CONVX_BASE 1038
#define PREP_GRID       13538

typedef __attribute__((ext_vector_type(8))) short short8;
typedef __attribute__((ext_vector_type(4))) float f32x4;

typedef const __attribute__((address_space(1))) void gvoid_t;
typedef __attribute__((address_space(3))) void lvoid_t;

__device__ __forceinline__ void load_lds16(const void* g, void* l) {
  __builtin_amdgcn_global_load_lds((gvoid_t*)g, (lvoid_t*)l, 16, 0, 0);
}

__device__ __forceinline__ unsigned short f2bf(float f) {
  __hip_bfloat16 h = __float2bfloat16(f);
  return *(unsigned short*)&h;
}
__device__ __forceinline__ float bflo(unsigned u) { return __uint_as_float(u << 16); }
__device__ __forceinline__ float bfhi(unsigned u) { return __uint_as_float(u & 0xffff0000u); }

// ---- fused prep: binA edge-binning + conv_w + conv_x in ONE dispatch ----
// All three are mutually independent. binA blocks first so their
// atomic/latency-heavy work overlaps conv_x's pure streaming.
// LDS (binA's 53.2 KB) is declared for all blocks -> 2 blocks/CU; conv_x
// compensates with 2 in-flight float4 loads per thread (8 elems/thread).
__global__ __launch_bounds__(256) void prep_kernel(
    const float* __restrict__ x,  unsigned short* __restrict__ xb,
    const float* __restrict__ w,  unsigned short* __restrict__ wt,
    const int* __restrict__ src, const int* __restrict__ dst,
    const float* __restrict__ wgt,
    int* __restrict__ gcur, unsigned long long* __restrict__ region) {
  __shared__ unsigned long long staged[EPB_A];
  __shared__ unsigned short sbkt[EPB_A];
  __shared__ int lhist[NBKT];
  __shared__ int lstart[NBKT];
  __shared__ int lcur[NBKT];
  __shared__ int gb[NBKT];
  __shared__ int csum[256];

  const int bid = blockIdx.x;
  const int t = threadIdx.x;

  if (bid >= PREP_CONVX_BASE) {
    // ---------- conv_x: fp32 -> bf16, 8 elems/thread ----------
    size_t i = (size_t)(bid - PREP_CONVX_BASE) * 256 + t;   // 3.2M threads exactly
    size_t idx = i * 8;
    float4 va = *(const float4*)(x + idx);
    float4 vb = *(const float4*)(x + idx + 4);
    short8 o;
    o[0] = (short)f2bf(va.x); o[1] = (short)f2bf(va.y);
    o[2] = (short)f2bf(va.z); o[3] = (short)f2bf(va.w);
    o[4] = (short)f2bf(vb.x); o[5] = (short)f2bf(vb.y);
    o[6] = (short)f2bf(vb.z); o[7] = (short)f2bf(vb.w);
    *(short8*)(xb + idx) = o;
    return;
  }
  if (bid >= PREP_CONVW_BASE) {
    // ---------- conv_w: fp32 [K][N] -> bf16 transposed [N][K] ----------
    int t2 = (bid - PREP_CONVW_BASE) * 256 + t;   // 65536 threads
    int n = t2 >> 8, k = t2 & 255;
    wt[t2] = f2bf(w[k * 256 + n]);                // wt[n*256 + k]
    return;
  }

  // ---------- binA: bin edges into fixed-capacity bucket regions ----------
  // pack: [w:32][dstlow:7 @bit17][src:17]
  const int e0 = bid * EPB_A;
  const int ecnt = min(EPB_A, N_EDGES - e0);

  for (int i = t; i < NBKT; i += 256) lhist[i] = 0;
  __syncthreads();
  for (int k = t; k < ecnt; k += 256)
    atomicAdd(&lhist[dst[e0 + k] >> 7], 1);
  __syncthreads();

  // blocked exclusive scan of lhist -> lstart (thread t owns [4t, 4t+4))
  int i0 = 4 * t;
  int a0 = (i0 + 0 < NBKT) ? lhist[i0 + 0] : 0;
  int a1 = (i0 + 1 < NBKT) ? lhist[i0 + 1] : 0;
  int a2 = (i0 + 2 < NBKT) ? lhist[i0 + 2] : 0;
  int a3 = (i0 + 3 < NBKT) ? lhist[i0 + 3] : 0;
  int s = a0 + a1 + a2 + a3;
  csum[t] = s;
  __syncthreads();
  for (int off = 1; off < 256; off <<= 1) {
    int v = (t >= off) ? csum[t - off] : 0;
    __syncthreads();
    csum[t] += v;
    __syncthreads();
  }
  int base = csum[t] - s;
  if (i0 + 0 < NBKT) lstart[i0 + 0] = base; base += a0;
  if (i0 + 1 < NBKT) lstart[i0 + 1] = base; base += a1;
  if (i0 + 2 < NBKT) lstart[i0 + 2] = base; base += a2;
  if (i0 + 3 < NBKT) lstart[i0 + 3] = base;
  __syncthreads();

  for (int i = t; i < NBKT; i += 256) {
    int c = lhist[i];
    int off = c ? atomicAdd(&gcur[i], c) : 0;
    gb[i] = i * BCAP + off;
    lcur[i] = lstart[i];
  }
  __syncthreads();

  for (int k = t; k < ecnt; k += 256) {
    int d  = dst[e0 + k];
    int sr = src[e0 + k];
    float wv = wgt[e0 + k];
    int b = d >> 7;
    int p = atomicAdd(&lcur[b], 1);
    staged[p] = ((unsigned long long)__float_as_uint(wv) << 32) |
                ((unsigned)(d & 127) << 17) | (unsigned)sr;
    sbkt[p] = (unsigned short)b;
  }
  __syncthreads();

  for (int j = t; j < ecnt; j += 256) {
    int b = sbkt[j];
    int addr = gb[b] + (j - lstart[b]);
    if (addr < (b + 1) * BCAP) region[addr] = staged[j];  // overflow guard (never fires)
  }
}

// ---------------- MFMA GEMM: support = Xb @ Wt^T  (bf16 out) --------------
__global__ __launch_bounds__(256) void gemm_kernel(const unsigned short* __restrict__ xb,
                                                   const unsigned short* __restrict__ wt,
                                                   unsigned short* __restrict__ sup) {
  __shared__ unsigned short As[128 * 32];
  __shared__ unsigned short Bs[128 * 32];
  const int tid  = threadIdx.x;
  const int w    = tid >> 6;
  const int lane = tid & 63;
  const int quad = lane >> 4;
  const int l15  = lane & 15;
  const int wr   = w >> 1, wc = w & 1;
  const int m0 = blockIdx.x * 128;
  const int n0 = blockIdx.y * 128;

  f32x4 acc[4][4] = {};

  const int srow   = lane >> 2;
  const int schunk = (lane & 3) * 8;

  for (int kt = 0; kt < 256; kt += 32) {
#pragma unroll
    for (int i = 0; i < 2; ++i) {
      int r = w * 32 + i * 16 + srow;
      load_lds16(xb + ((size_t)(m0 + r) * 256 + kt + schunk),
                 As + (w * 32 + i * 16) * 32);
      load_lds16(wt + ((size_t)(n0 + r) * 256 + kt + schunk),
                 Bs + (w * 32 + i * 16) * 32);
    }
    __syncthreads();

    short8 a[4], b[4];
#pragma unroll
    for (int mi = 0; mi < 4; ++mi)
      a[mi] = *(const short8*)(As + (wr * 64 + mi * 16 + l15) * 32 + quad * 8);
#pragma unroll
    for (int ni = 0; ni < 4; ++ni)
      b[ni] = *(const short8*)(Bs + (wc * 64 + ni * 16 + l15) * 32 + quad * 8);

#pragma unroll
    for (int mi = 0; mi < 4; ++mi)
#pragma unroll
      for (int ni = 0; ni < 4; ++ni)
        acc[mi][ni] = __builtin_amdgcn_mfma_f32_16x16x32_bf16(a[mi], b[ni], acc[mi][ni], 0, 0, 0);
    __syncthreads();
  }

#pragma unroll
  for (int mi = 0; mi < 4; ++mi) {
#pragma unroll
    for (int r = 0; r < 4; ++r) {
      size_t row = (size_t)(m0 + wr * 64 + mi * 16 + quad * 4 + r);
#pragma unroll
      for (int ni = 0; ni < 4; ++ni) {
        int col = n0 + wc * 64 + ni * 16 + l15;
        sup[row * 256 + col] = f2bf(acc[mi][ni][r]);
      }
    }
  }
}

// ---- fused sort + gather, ROW-SPLIT: grid (782, 2), 256 threads ----
// Block (b, h) sorts only the 64 dsts of half-bucket h into a 19.5 KB LDS
// list, then 4 waves gather 16 dsts each. 1564 blocks, 20 KB LDS ->
// 8 blocks/CU capacity -> ALL blocks resident (~28 waves/CU vs 20 before).
__global__ __launch_bounds__(256) void csr_gather_kernel(
    const unsigned long long* __restrict__ region,
    const int* __restrict__ gcur,
    const unsigned short* __restrict__ sup,
    const float* __restrict__ bias,
    float* __restrict__ out) {
  __shared__ unsigned long long lcsr[GCAP];
  __shared__ int lhist[64], loff[64], lcur[64];
  const int t = threadIdx.x;
  const int b = blockIdx.x;
  const int h = blockIdx.y;          // half: dsts [h*64, h*64+64)
  const int cnt = min(gcur[b], BCAP);
  const int base = b * BCAP;

  // --- counting sort (this half only) into lcsr ---
  if (t < 64) lhist[t] = 0;
  __syncthreads();
  for (int j = t; j < cnt; j += 256) {
    unsigned lo = (unsigned)(region[base + j] & 0xffffffffu);
    int dl = (int)((lo >> 17) & 127);
    if ((dl >> 6) == h) atomicAdd(&lhist[dl & 63], 1);
  }
  __syncthreads();
  if (t < 64) loff[t] = lhist[t];
  __syncthreads();
  for (int off = 1; off < 64; off <<= 1) {
    int v = (t >= off && t < 64) ? loff[t - off] : 0;
    __syncthreads();
    if (t < 64) loff[t] += v;
    __syncthreads();
  }
  if (t < 64) { loff[t] -= lhist[t]; lcur[t] = loff[t]; }
  __syncthreads();
  for (int j = t; j < cnt; j += 256) {
    unsigned long long e = region[base + j];
    int dl = (int)((e >> 17) & 127);
    if ((dl >> 6) == h) {
      int p = atomicAdd(&lcur[dl & 63], 1);
      if (p < GCAP) lcsr[p] = e;   // overflow guard (never fires)
    }
  }
  __syncthreads();

  // --- gather: edge records broadcast from LDS, sup rows from global ---
  const int wv = t >> 6;
  const int c0 = (t & 63) * 4;
  float4 bv = *(const float4*)(bias + c0);

  for (int dl = wv; dl < 64; dl += 4) {
    int node = b * 128 + h * 64 + dl;
    if (node >= N_NODES) continue;   // wave-uniform
    int start = loff[dl];
    int end   = min(lcur[dl], GCAP);
    float a0 = bv.x, a1 = bv.y, a2 = bv.z, a3 = bv.w;

    int i = start;
    for (; i + 2 <= end; i += 2) {
      unsigned long long m0 = lcsr[i];
      unsigned long long m1 = lcsr[i + 1];
      int   s0 = (int)(m0 & 0x1ffffu);
      float w0 = __uint_as_float((unsigned)(m0 >> 32));
      int   s1 = (int)(m1 & 0x1ffffu);
      float w1 = __uint_as_float((unsigned)(m1 >> 32));
      uint2 p0 = *(const uint2*)(sup + (size_t)s0 * 256 + c0);
      uint2 p1 = *(const uint2*)(sup + (size_t)s1 * 256 + c0);
      a0 = fmaf(w0, bflo(p0.x), a0);
      a1 = fmaf(w0, bfhi(p0.x), a1);
      a2 = fmaf(w0, bflo(p0.y), a2);
      a3 = fmaf(w0, bfhi(p0.y), a3);
      a0 = fmaf(w1, bflo(p1.x), a0);
      a1 = fmaf(w1, bfhi(p1.x), a1);
      a2 = fmaf(w1, bflo(p1.y), a2);
      a3 = fmaf(w1, bfhi(p1.y), a3);
    }
    if (i < end) {
      unsigned long long m0 = lcsr[i];
      int   s0 = (int)(m0 & 0x1ffffu);
      float w0 = __uint_as_float((unsigned)(m0 >> 32));
      uint2 p0 = *(const uint2*)(sup + (size_t)s0 * 256 + c0);
      a0 = fmaf(w0, bflo(p0.x), a0);
      a1 = fmaf(w0, bfhi(p0.x), a1);
      a2 = fmaf(w0, bflo(p0.y), a2);
      a3 = fmaf(w0, bfhi(p0.y), a3);
    }
    *(float4*)(out + (size_t)node * 256 + c0) = make_float4(a0, a1, a2, a3);
  }
}

extern "C" void kernel_launch(void* const* d_in, const int* in_sizes, int n_in,
                              void* d_out, int out_size, void* d_ws, size_t ws_size,
                              hipStream_t stream) {
  const float* x        = (const float*)d_in[0];
  const int*   edge_src = (const int*)d_in[1];
  const int*   edge_dst = (const int*)d_in[2];
  const float* edge_w   = (const float*)d_in[3];
  const float* weight   = (const float*)d_in[4];
  const float* bias     = (const float*)d_in[5];
  float* out = (float*)d_out;

  char* ws = (char*)d_ws;
  size_t off = 0;
  auto alloc = [&](size_t bytes) -> void* {
    void* p = ws + off;
    off = (off + bytes + 255) & ~(size_t)255;
    return p;
  };

  unsigned short* wt  = (unsigned short*)alloc(256 * 256 * 2);
  unsigned short* sup = (unsigned short*)alloc((size_t)M_PAD * 256 * 2);      // 51.25 MB
  unsigned long long* region = (unsigned long long*)alloc((size_t)NBKT * BCAP * 8);  // 28.84 MB
  int* gcur = (int*)alloc(NBKT * 4);

  // xb scratch lives in d_out (102.4 MB): dead before csr_gather writes out.
  // Pad rows [100000,100096) read as poison -> poison only sup rows >= N_NODES,
  // which are never referenced (src < 100000, node-guard in gather).
  unsigned short* xb = (unsigned short*)d_out;

  hipMemsetAsync(gcur, 0, NBKT * 4, stream);
  prep_kernel<<<PREP_GRID, 256, 0, stream>>>(x, xb, weight, wt,
                                             edge_src, edge_dst, edge_w,
                                             gcur, region);
  gemm_kernel<<<dim3(782, 2), 256, 0, stream>>>(xb, wt, sup);
  csr_gather_kernel<<<dim3(NBKT, 2), 256, 0, stream>>>(region, gcur, sup, bias, out);
}

// Round 4
// 504.143 us; speedup vs baseline: 1.0657x; 1.0063x over previous
//
#include <hip/hip_runtime.h>
#include <hip/hip_bf16.h>

#define N_NODES 100000
#define N_EDGES 3200000
#define DDIM    256
#define M_PAD   100096   // 782 * 128
#define NBKT    782      // buckets = dst >> 7 (128 dsts per bucket)
#define BCAP    4608     // mean 4096 + 8 sigma
#define EPB     2048     // edges per binA block (shrunk for LDS union)
#define NB_BINA 1563     // ceil(3.2M / 2048)
#define NB_GEMM 1564     // 782 * 2
#define GCAP    2432     // half-bucket capacity: mean 2048 + 8.5 sigma

typedef __attribute__((ext_vector_type(8))) short short8;
typedef __attribute__((ext_vector_type(4))) float f32x4;

typedef const __attribute__((address_space(1))) void gvoid_t;
typedef __attribute__((address_space(3))) void lvoid_t;

__device__ __forceinline__ void load_lds16(const void* g, void* l) {
  __builtin_amdgcn_global_load_lds((gvoid_t*)g, (lvoid_t*)l, 16, 0, 0);
}

__device__ __forceinline__ unsigned short f2bf(float f) {
  __hip_bfloat16 h = __float2bfloat16(f);
  return *(unsigned short*)&h;
}
__device__ __forceinline__ float bflo(unsigned u) { return __uint_as_float(u << 16); }
__device__ __forceinline__ float bfhi(unsigned u) { return __uint_as_float(u & 0xffff0000u); }

// ---- dispatch 1: conv_w (fp32 [K][N] -> bf16 transposed [N][K]) + gcur init ----
__global__ void convw_kernel(const float* __restrict__ w, unsigned short* __restrict__ wt,
                             int* __restrict__ gcur) {
  int t = blockIdx.x * blockDim.x + threadIdx.x;   // 65536 threads
  int n = t >> 8, k = t & 255;
  wt[t] = f2bf(w[k * 256 + n]);                    // wt[n*256 + k]
  if (t < NBKT) gcur[t] = 0;
}

// ---- dispatch 2: fused binA (edge binning) + MFMA GEMM, one grid ----
// binA and gemm are mutually independent; fusing overlaps binA's
// atomic/latency-heavy work with gemm's MFMA/staging work.
// Union LDS 34 KB -> 4 blocks/CU for both block types.
// gemm reads x (fp32) DIRECTLY, converting to bf16 in-register during
// A-staging: conv_x kernel + xb buffer (153 MB traffic) eliminated.
__global__ __launch_bounds__(256) void gemm_binA_kernel(
    const float* __restrict__ x, const unsigned short* __restrict__ wt,
    unsigned short* __restrict__ sup,
    const int* __restrict__ src, const int* __restrict__ dst,
    const float* __restrict__ wgt,
    int* __restrict__ gcur, unsigned long long* __restrict__ region) {
  __shared__ __align__(16) char smem[34816];
  const int bid = blockIdx.x;
  const int t = threadIdx.x;

  if (bid >= NB_BINA) {
    // ================= GEMM: sup = bf16(x) @ wt^T =================
    unsigned short* As = (unsigned short*)smem;            // 128*32 bf16 = 8 KB
    unsigned short* Bs = (unsigned short*)(smem + 8192);   // 8 KB
    const int g  = bid - NB_BINA;
    const int m0 = (g >> 1) * 128;
    const int n0 = (g & 1) * 128;
    const int w    = t >> 6;
    const int lane = t & 63;
    const int quad = lane >> 4;
    const int l15  = lane & 15;
    const int wr   = w >> 1, wc = w & 1;
    const int srow   = lane >> 2;
    const int schunk = (lane & 3) * 8;

    f32x4 acc[4][4] = {};

    for (int kt = 0; kt < 256; kt += 32) {
      // A: reg-stage fp32 -> bf16 (4 float4 loads / thread)
#pragma unroll
      for (int j = 0; j < 4; ++j) {
        int f = j * 256 + t;            // 1024 float4 cover 128x32 fp32
        int row = f >> 3, c4 = (f & 7) * 4;
        int xr = m0 + row; if (xr >= N_NODES) xr = N_NODES - 1;   // clamp pad rows
        float4 v = *(const float4*)(x + (size_t)xr * 256 + kt + c4);
        ushort4 o;
        o.x = f2bf(v.x); o.y = f2bf(v.y); o.z = f2bf(v.z); o.w = f2bf(v.w);
        *(ushort4*)(As + row * 32 + c4) = o;
      }
      // B: async global->LDS (bf16 already)
#pragma unroll
      for (int i = 0; i < 2; ++i) {
        int r = w * 32 + i * 16 + srow;
        load_lds16(wt + ((size_t)(n0 + r) * 256 + kt + schunk),
                   Bs + (w * 32 + i * 16) * 32);
      }
      __syncthreads();

      short8 a[4], b[4];
#pragma unroll
      for (int mi = 0; mi < 4; ++mi)
        a[mi] = *(const short8*)(As + (wr * 64 + mi * 16 + l15) * 32 + quad * 8);
#pragma unroll
      for (int ni = 0; ni < 4; ++ni)
        b[ni] = *(const short8*)(Bs + (wc * 64 + ni * 16 + l15) * 32 + quad * 8);

#pragma unroll
      for (int mi = 0; mi < 4; ++mi)
#pragma unroll
        for (int ni = 0; ni < 4; ++ni)
          acc[mi][ni] = __builtin_amdgcn_mfma_f32_16x16x32_bf16(a[mi], b[ni], acc[mi][ni], 0, 0, 0);
      __syncthreads();
    }

#pragma unroll
    for (int mi = 0; mi < 4; ++mi) {
#pragma unroll
      for (int r = 0; r < 4; ++r) {
        size_t row = (size_t)(m0 + wr * 64 + mi * 16 + quad * 4 + r);
#pragma unroll
        for (int ni = 0; ni < 4; ++ni) {
          int col = n0 + wc * 64 + ni * 16 + l15;
          sup[row * 256 + col] = f2bf(acc[mi][ni][r]);
        }
      }
    }
    return;
  }

  // ================= binA: bin edges into bucket regions =================
  // pack: [w:32][dstlow:7 @bit17][src:17]
  unsigned long long* staged = (unsigned long long*)smem;     // 2048*8 = 16384
  unsigned short* sbkt = (unsigned short*)(smem + 16384);     // 2048*2 =  4096
  int* lhist  = (int*)(smem + 20480);                         // 782*4 = 3128
  int* lstart = (int*)(smem + 23608);
  int* lcur   = (int*)(smem + 26736);
  int* gb     = (int*)(smem + 29864);
  int* csum   = (int*)(smem + 32992);                         // 256*4 -> end 34016

  const int e0 = bid * EPB;
  const int ecnt = min(EPB, N_EDGES - e0);

  for (int i = t; i < NBKT; i += 256) lhist[i] = 0;
  __syncthreads();
  for (int k = t; k < ecnt; k += 256)
    atomicAdd(&lhist[dst[e0 + k] >> 7], 1);
  __syncthreads();

  // blocked exclusive scan of lhist -> lstart (thread t owns [4t, 4t+4))
  int i0 = 4 * t;
  int a0 = (i0 + 0 < NBKT) ? lhist[i0 + 0] : 0;
  int a1 = (i0 + 1 < NBKT) ? lhist[i0 + 1] : 0;
  int a2 = (i0 + 2 < NBKT) ? lhist[i0 + 2] : 0;
  int a3 = (i0 + 3 < NBKT) ? lhist[i0 + 3] : 0;
  int s = a0 + a1 + a2 + a3;
  csum[t] = s;
  __syncthreads();
  for (int off = 1; off < 256; off <<= 1) {
    int v = (t >= off) ? csum[t - off] : 0;
    __syncthreads();
    csum[t] += v;
    __syncthreads();
  }
  int base = csum[t] - s;
  if (i0 + 0 < NBKT) lstart[i0 + 0] = base; base += a0;
  if (i0 + 1 < NBKT) lstart[i0 + 1] = base; base += a1;
  if (i0 + 2 < NBKT) lstart[i0 + 2] = base; base += a2;
  if (i0 + 3 < NBKT) lstart[i0 + 3] = base;
  __syncthreads();

  for (int i = t; i < NBKT; i += 256) {
    int c = lhist[i];
    int off = c ? atomicAdd(&gcur[i], c) : 0;
    gb[i] = i * BCAP + off;
    lcur[i] = lstart[i];
  }
  __syncthreads();

  for (int k = t; k < ecnt; k += 256) {
    int d  = dst[e0 + k];
    int sr = src[e0 + k];
    float wv = wgt[e0 + k];
    int b = d >> 7;
    int p = atomicAdd(&lcur[b], 1);
    staged[p] = ((unsigned long long)__float_as_uint(wv) << 32) |
                ((unsigned)(d & 127) << 17) | (unsigned)sr;
    sbkt[p] = (unsigned short)b;
  }
  __syncthreads();

  for (int j = t; j < ecnt; j += 256) {
    int b = sbkt[j];
    int addr = gb[b] + (j - lstart[b]);
    if (addr < (b + 1) * BCAP) region[addr] = staged[j];  // overflow guard (never fires)
  }
}

// ---- dispatch 3: fused sort + gather, row-split: grid (782, 2), 256 thr ----
__global__ __launch_bounds__(256) void csr_gather_kernel(
    const unsigned long long* __restrict__ region,
    const int* __restrict__ gcur,
    const unsigned short* __restrict__ sup,
    const float* __restrict__ bias,
    float* __restrict__ out) {
  __shared__ unsigned long long lcsr[GCAP];
  __shared__ int lhist[64], loff[64], lcur[64];
  const int t = threadIdx.x;
  const int b = blockIdx.x;
  const int h = blockIdx.y;          // half: dsts [h*64, h*64+64)
  const int cnt = min(gcur[b], BCAP);
  const int base = b * BCAP;

  // --- counting sort (this half only) into lcsr ---
  if (t < 64) lhist[t] = 0;
  __syncthreads();
  for (int j = t; j < cnt; j += 256) {
    unsigned lo = (unsigned)(region[base + j] & 0xffffffffu);
    int dl = (int)((lo >> 17) & 127);
    if ((dl >> 6) == h) atomicAdd(&lhist[dl & 63], 1);
  }
  __syncthreads();
  if (t < 64) loff[t] = lhist[t];
  __syncthreads();
  for (int off = 1; off < 64; off <<= 1) {
    int v = (t >= off && t < 64) ? loff[t - off] : 0;
    __syncthreads();
    if (t < 64) loff[t] += v;
    __syncthreads();
  }
  if (t < 64) { loff[t] -= lhist[t]; lcur[t] = loff[t]; }
  __syncthreads();
  for (int j = t; j < cnt; j += 256) {
    unsigned long long e = region[base + j];
    int dl = (int)((e >> 17) & 127);
    if ((dl >> 6) == h) {
      int p = atomicAdd(&lcur[dl & 63], 1);
      if (p < GCAP) lcsr[p] = e;   // overflow guard (never fires)
    }
  }
  __syncthreads();

  // --- gather: edge records broadcast from LDS, sup rows from global ---
  const int wv = t >> 6;
  const int c0 = (t & 63) * 4;
  float4 bv = *(const float4*)(bias + c0);

  for (int dl = wv; dl < 64; dl += 4) {
    int node = b * 128 + h * 64 + dl;
    if (node >= N_NODES) continue;   // wave-uniform
    int start = loff[dl];
    int end   = min(lcur[dl], GCAP);
    float a0 = bv.x, a1 = bv.y, a2 = bv.z, a3 = bv.w;

    int i = start;
    for (; i + 2 <= end; i += 2) {
      unsigned long long m0 = lcsr[i];
      unsigned long long m1 = lcsr[i + 1];
      int   s0 = (int)(m0 & 0x1ffffu);
      float w0 = __uint_as_float((unsigned)(m0 >> 32));
      int   s1 = (int)(m1 & 0x1ffffu);
      float w1 = __uint_as_float((unsigned)(m1 >> 32));
      uint2 p0 = *(const uint2*)(sup + (size_t)s0 * 256 + c0);
      uint2 p1 = *(const uint2*)(sup + (size_t)s1 * 256 + c0);
      a0 = fmaf(w0, bflo(p0.x), a0);
      a1 = fmaf(w0, bfhi(p0.x), a1);
      a2 = fmaf(w0, bflo(p0.y), a2);
      a3 = fmaf(w0, bfhi(p0.y), a3);
      a0 = fmaf(w1, bflo(p1.x), a0);
      a1 = fmaf(w1, bfhi(p1.x), a1);
      a2 = fmaf(w1, bflo(p1.y), a2);
      a3 = fmaf(w1, bfhi(p1.y), a3);
    }
    if (i < end) {
      unsigned long long m0 = lcsr[i];
      int   s0 = (int)(m0 & 0x1ffffu);
      float w0 = __uint_as_float((unsigned)(m0 >> 32));
      uint2 p0 = *(const uint2*)(sup + (size_t)s0 * 256 + c0);
      a0 = fmaf(w0, bflo(p0.x), a0);
      a1 = fmaf(w0, bfhi(p0.x), a1);
      a2 = fmaf(w0, bflo(p0.y), a2);
      a3 = fmaf(w0, bfhi(p0.y), a3);
    }
    *(float4*)(out + (size_t)node * 256 + c0) = make_float4(a0, a1, a2, a3);
  }
}

extern "C" void kernel_launch(void* const* d_in, const int* in_sizes, int n_in,
                              void* d_out, int out_size, void* d_ws, size_t ws_size,
                              hipStream_t stream) {
  const float* x        = (const float*)d_in[0];
  const int*   edge_src = (const int*)d_in[1];
  const int*   edge_dst = (const int*)d_in[2];
  const float* edge_w   = (const float*)d_in[3];
  const float* weight   = (const float*)d_in[4];
  const float* bias     = (const float*)d_in[5];
  float* out = (float*)d_out;

  char* ws = (char*)d_ws;
  size_t off = 0;
  auto alloc = [&](size_t bytes) -> void* {
    void* p = ws + off;
    off = (off + bytes + 255) & ~(size_t)255;
    return p;
  };

  unsigned short* wt  = (unsigned short*)alloc(256 * 256 * 2);
  unsigned short* sup = (unsigned short*)alloc((size_t)M_PAD * 256 * 2);             // 51.25 MB
  unsigned long long* region = (unsigned long long*)alloc((size_t)NBKT * BCAP * 8);  // 28.84 MB
  int* gcur = (int*)alloc(NBKT * 4);

  convw_kernel<<<256, 256, 0, stream>>>(weight, wt, gcur);
  gemm_binA_kernel<<<NB_BINA + NB_GEMM, 256, 0, stream>>>(x, wt, sup,
                                                          edge_src, edge_dst, edge_w,
                                                          gcur, region);
  csr_gather_kernel<<<dim3(NBKT, 2), 256, 0, stream>>>(region, gcur, sup, bias, out);
}

// Round 5
// 495.114 us; speedup vs baseline: 1.0851x; 1.0182x over previous
//
#include <hip/hip_runtime.h>
#include <hip/hip_bf16.h>

#define N_NODES 100000
#define N_EDGES 3200000
#define DDIM    256
#define M_PAD   100096   // 782 * 128
#define NBKT    782      // buckets = dst >> 7 (128 dsts per bucket)
#define BCAP    4608     // mean 4096 + 8 sigma
#define EPB     4096     // edges per binA block
#define NB_BINA 782      // ceil(3.2M / 4096)
#define NB_GEMM 1564     // 782 * 2
#define GCAP    2432     // half-bucket capacity: mean 2048 + 8.5 sigma
#define SMEM_BYTES 50432 // union: binA 50344 | gemm 32768 -> 3 blocks/CU

typedef __attribute__((ext_vector_type(8))) short short8;
typedef __attribute__((ext_vector_type(4))) float f32x4;

typedef const __attribute__((address_space(1))) void gvoid_t;
typedef __attribute__((address_space(3))) void lvoid_t;

__device__ __forceinline__ void load_lds16(const void* g, void* l) {
  __builtin_amdgcn_global_load_lds((gvoid_t*)g, (lvoid_t*)l, 16, 0, 0);
}

__device__ __forceinline__ unsigned short f2bf(float f) {
  __hip_bfloat16 h = __float2bfloat16(f);
  return *(unsigned short*)&h;
}
__device__ __forceinline__ float bflo(unsigned u) { return __uint_as_float(u << 16); }
__device__ __forceinline__ float bfhi(unsigned u) { return __uint_as_float(u & 0xffff0000u); }

// ---- dispatch 1: conv_w (fp32 [K][N] -> bf16 transposed [N][K]) + gcur init ----
__global__ void convw_kernel(const float* __restrict__ w, unsigned short* __restrict__ wt,
                             int* __restrict__ gcur) {
  int t = blockIdx.x * blockDim.x + threadIdx.x;   // 65536 threads
  int n = t >> 8, k = t & 255;
  wt[t] = f2bf(w[k * 256 + n]);                    // wt[n*256 + k]
  if (t < NBKT) gcur[t] = 0;
}

// ---- dispatch 2: fused binA (EPB=4096, LDS-overlaid) + pipelined MFMA GEMM ----
// binA and gemm are independent; one dispatch overlaps them.
// GEMM: 2-deep pipeline (double-buffered As/Bs, 1 barrier/K-step, A-loads
// issued one step ahead so HBM latency hides under ds_read+MFMA).
// binA: EPB back to 4096 (halves global atomics + scatter segments);
// lhist/csum alias the staged[] area (dead until they retire) -> 50.3 KB.
__global__ __launch_bounds__(256, 3) void gemm_binA_kernel(
    const float* __restrict__ x, const unsigned short* __restrict__ wt,
    unsigned short* __restrict__ sup,
    const int* __restrict__ src, const int* __restrict__ dst,
    const float* __restrict__ wgt,
    int* __restrict__ gcur, unsigned long long* __restrict__ region) {
  __shared__ __align__(16) char smem[SMEM_BYTES];
  const int bid = blockIdx.x;
  const int t = threadIdx.x;

  if (bid >= NB_BINA) {
    // ================= GEMM: sup = bf16(x) @ wt^T =================
    unsigned short* As0 = (unsigned short*)smem;             // 8 KB each
    unsigned short* Bs0 = (unsigned short*)(smem + 8192);
    unsigned short* As1 = (unsigned short*)(smem + 16384);
    unsigned short* Bs1 = (unsigned short*)(smem + 24576);
    const int g  = bid - NB_BINA;
    const int m0 = (g >> 1) * 128;
    const int n0 = (g & 1) * 128;
    const int w    = t >> 6;
    const int lane = t & 63;
    const int quad = lane >> 4;
    const int l15  = lane & 15;
    const int wr   = w >> 1, wc = w & 1;
    const int srow   = lane >> 2;
    const int schunk = (lane & 3) * 8;

    f32x4 acc[4][4] = {};

#define A_LOAD(kt, va)                                                        \
    do { _Pragma("unroll")                                                    \
      for (int j = 0; j < 4; ++j) {                                           \
        int row = j * 32 + (t >> 3);                                          \
        int xr = m0 + row; if (xr >= N_NODES) xr = N_NODES - 1;               \
        va[j] = *(const float4*)(x + (size_t)xr * 256 + (kt) + (t & 7) * 4);  \
      } } while (0)
#define A_STORE(va, asb)                                                      \
    do { _Pragma("unroll")                                                    \
      for (int j = 0; j < 4; ++j) {                                           \
        int row = j * 32 + (t >> 3);                                          \
        ushort4 o;                                                            \
        o.x = f2bf(va[j].x); o.y = f2bf(va[j].y);                             \
        o.z = f2bf(va[j].z); o.w = f2bf(va[j].w);                             \
        *(ushort4*)((asb) + row * 32 + (t & 7) * 4) = o;                      \
      } } while (0)
#define B_LOAD(kt, bsb)                                                       \
    do { _Pragma("unroll")                                                    \
      for (int i = 0; i < 2; ++i) {                                           \
        int r = w * 32 + i * 16 + srow;                                       \
        load_lds16(wt + ((size_t)(n0 + r) * 256 + (kt) + schunk),             \
                   (bsb) + (w * 32 + i * 16) * 32);                           \
      } } while (0)
#define COMPUTE(asb, bsb)                                                     \
    do {                                                                      \
      short8 a[4], b[4];                                                      \
      _Pragma("unroll")                                                       \
      for (int mi = 0; mi < 4; ++mi)                                          \
        a[mi] = *(const short8*)((asb) + (wr * 64 + mi * 16 + l15) * 32 + quad * 8); \
      _Pragma("unroll")                                                       \
      for (int ni = 0; ni < 4; ++ni)                                          \
        b[ni] = *(const short8*)((bsb) + (wc * 64 + ni * 16 + l15) * 32 + quad * 8); \
      _Pragma("unroll")                                                       \
      for (int mi = 0; mi < 4; ++mi)                                          \
        _Pragma("unroll")                                                     \
        for (int ni = 0; ni < 4; ++ni)                                        \
          acc[mi][ni] = __builtin_amdgcn_mfma_f32_16x16x32_bf16(a[mi], b[ni], acc[mi][ni], 0, 0, 0); \
    } while (0)

    {
      float4 va[4];
      A_LOAD(0, va);
      A_STORE(va, As0);
      B_LOAD(0, Bs0);
    }
    __syncthreads();
    for (int kp = 0; kp < 4; ++kp) {
      const int kt1 = kp * 64 + 32;
      {
        float4 va[4];
        A_LOAD(kt1, va);          // issue next-step loads first
        COMPUTE(As0, Bs0);        // latency hides under ds_read+MFMA
        A_STORE(va, As1);
        B_LOAD(kt1, Bs1);
      }
      __syncthreads();
      if (kp < 3) {
        const int kt2 = kp * 64 + 64;
        float4 vb[4];
        A_LOAD(kt2, vb);
        COMPUTE(As1, Bs1);
        A_STORE(vb, As0);
        B_LOAD(kt2, Bs0);
      } else {
        COMPUTE(As1, Bs1);
      }
      __syncthreads();
    }

#pragma unroll
    for (int mi = 0; mi < 4; ++mi) {
#pragma unroll
      for (int r = 0; r < 4; ++r) {
        size_t row = (size_t)(m0 + wr * 64 + mi * 16 + quad * 4 + r);
#pragma unroll
        for (int ni = 0; ni < 4; ++ni) {
          int col = n0 + wc * 64 + ni * 16 + l15;
          sup[row * 256 + col] = f2bf(acc[mi][ni][r]);
        }
      }
    }
    return;
  }

  // ================= binA: bin edges into bucket regions =================
  // pack: [w:32][dstlow:7 @bit17][src:17]
  // LDS overlay: lhist/csum live inside staged[] (staged written only after
  // both are dead; __syncthreads separates the phases).
  unsigned long long* staged = (unsigned long long*)smem;        // [0, 32768)
  unsigned short* sbkt = (unsigned short*)(smem + 32768);        // [32768, 40960)
  int* lstart = (int*)(smem + 40960);                            // 782*4
  int* lcur   = (int*)(smem + 44088);
  int* gb     = (int*)(smem + 47216);                            // ends 50344
  int* lhist  = (int*)smem;                                      // alias: [0, 3128)
  int* csum   = (int*)(smem + 3200);                             // alias: [3200, 4224)

  const int e0 = bid * EPB;
  const int ecnt = min(EPB, N_EDGES - e0);

  for (int i = t; i < NBKT; i += 256) lhist[i] = 0;
  __syncthreads();
  for (int k = t; k < ecnt; k += 256)
    atomicAdd(&lhist[dst[e0 + k] >> 7], 1);
  __syncthreads();

  // blocked exclusive scan of lhist -> lstart (thread t owns [4t, 4t+4))
  int i0 = 4 * t;
  int a0 = (i0 + 0 < NBKT) ? lhist[i0 + 0] : 0;
  int a1 = (i0 + 1 < NBKT) ? lhist[i0 + 1] : 0;
  int a2 = (i0 + 2 < NBKT) ? lhist[i0 + 2] : 0;
  int a3 = (i0 + 3 < NBKT) ? lhist[i0 + 3] : 0;
  int s = a0 + a1 + a2 + a3;
  csum[t] = s;
  __syncthreads();
  for (int off = 1; off < 256; off <<= 1) {
    int v = (t >= off) ? csum[t - off] : 0;
    __syncthreads();
    csum[t] += v;
    __syncthreads();
  }
  int base = csum[t] - s;
  if (i0 + 0 < NBKT) lstart[i0 + 0] = base; base += a0;
  if (i0 + 1 < NBKT) lstart[i0 + 1] = base; base += a1;
  if (i0 + 2 < NBKT) lstart[i0 + 2] = base; base += a2;
  if (i0 + 3 < NBKT) lstart[i0 + 3] = base;
  __syncthreads();

  for (int i = t; i < NBKT; i += 256) {
    int c = lhist[i];
    int off = c ? atomicAdd(&gcur[i], c) : 0;
    gb[i] = i * BCAP + off;
    lcur[i] = lstart[i];
  }
  __syncthreads();   // lhist/csum dead past here; staged may now be written

  for (int k = t; k < ecnt; k += 256) {
    int d  = dst[e0 + k];
    int sr = src[e0 + k];
    float wv = wgt[e0 + k];
    int b = d >> 7;
    int p = atomicAdd(&lcur[b], 1);
    staged[p] = ((unsigned long long)__float_as_uint(wv) << 32) |
                ((unsigned)(d & 127) << 17) | (unsigned)sr;
    sbkt[p] = (unsigned short)b;
  }
  __syncthreads();

  for (int j = t; j < ecnt; j += 256) {
    int b = sbkt[j];
    int addr = gb[b] + (j - lstart[b]);
    if (addr < (b + 1) * BCAP) region[addr] = staged[j];  // overflow guard (never fires)
  }
}

// ---- dispatch 3: fused sort + gather, row-split: grid (782, 2), 256 thr ----
// UNCHANGED from round 3/4 (control).
__global__ __launch_bounds__(256) void csr_gather_kernel(
    const unsigned long long* __restrict__ region,
    const int* __restrict__ gcur,
    const unsigned short* __restrict__ sup,
    const float* __restrict__ bias,
    float* __restrict__ out) {
  __shared__ unsigned long long lcsr[GCAP];
  __shared__ int lhist[64], loff[64], lcur[64];
  const int t = threadIdx.x;
  const int b = blockIdx.x;
  const int h = blockIdx.y;          // half: dsts [h*64, h*64+64)
  const int cnt = min(gcur[b], BCAP);
  const int base = b * BCAP;

  // --- counting sort (this half only) into lcsr ---
  if (t < 64) lhist[t] = 0;
  __syncthreads();
  for (int j = t; j < cnt; j += 256) {
    unsigned lo = (unsigned)(region[base + j] & 0xffffffffu);
    int dl = (int)((lo >> 17) & 127);
    if ((dl >> 6) == h) atomicAdd(&lhist[dl & 63], 1);
  }
  __syncthreads();
  if (t < 64) loff[t] = lhist[t];
  __syncthreads();
  for (int off = 1; off < 64; off <<= 1) {
    int v = (t >= off && t < 64) ? loff[t - off] : 0;
    __syncthreads();
    if (t < 64) loff[t] += v;
    __syncthreads();
  }
  if (t < 64) { loff[t] -= lhist[t]; lcur[t] = loff[t]; }
  __syncthreads();
  for (int j = t; j < cnt; j += 256) {
    unsigned long long e = region[base + j];
    int dl = (int)((e >> 17) & 127);
    if ((dl >> 6) == h) {
      int p = atomicAdd(&lcur[dl & 63], 1);
      if (p < GCAP) lcsr[p] = e;   // overflow guard (never fires)
    }
  }
  __syncthreads();

  // --- gather: edge records broadcast from LDS, sup rows from global ---
  const int wv = t >> 6;
  const int c0 = (t & 63) * 4;
  float4 bv = *(const float4*)(bias + c0);

  for (int dl = wv; dl < 64; dl += 4) {
    int node = b * 128 + h * 64 + dl;
    if (node >= N_NODES) continue;   // wave-uniform
    int start = loff[dl];
    int end   = min(lcur[dl], GCAP);
    float a0 = bv.x, a1 = bv.y, a2 = bv.z, a3 = bv.w;

    int i = start;
    for (; i + 2 <= end; i += 2) {
      unsigned long long m0 = lcsr[i];
      unsigned long long m1 = lcsr[i + 1];
      int   s0 = (int)(m0 & 0x1ffffu);
      float w0 = __uint_as_float((unsigned)(m0 >> 32));
      int   s1 = (int)(m1 & 0x1ffffu);
      float w1 = __uint_as_float((unsigned)(m1 >> 32));
      uint2 p0 = *(const uint2*)(sup + (size_t)s0 * 256 + c0);
      uint2 p1 = *(const uint2*)(sup + (size_t)s1 * 256 + c0);
      a0 = fmaf(w0, bflo(p0.x), a0);
      a1 = fmaf(w0, bfhi(p0.x), a1);
      a2 = fmaf(w0, bflo(p0.y), a2);
      a3 = fmaf(w0, bfhi(p0.y), a3);
      a0 = fmaf(w1, bflo(p1.x), a0);
      a1 = fmaf(w1, bfhi(p1.x), a1);
      a2 = fmaf(w1, bflo(p1.y), a2);
      a3 = fmaf(w1, bfhi(p1.y), a3);
    }
    if (i < end) {
      unsigned long long m0 = lcsr[i];
      int   s0 = (int)(m0 & 0x1ffffu);
      float w0 = __uint_as_float((unsigned)(m0 >> 32));
      uint2 p0 = *(const uint2*)(sup + (size_t)s0 * 256 + c0);
      a0 = fmaf(w0, bflo(p0.x), a0);
      a1 = fmaf(w0, bfhi(p0.x), a1);
      a2 = fmaf(w0, bflo(p0.y), a2);
      a3 = fmaf(w0, bfhi(p0.y), a3);
    }
    *(float4*)(out + (size_t)node * 256 + c0) = make_float4(a0, a1, a2, a3);
  }
}

extern "C" void kernel_launch(void* const* d_in, const int* in_sizes, int n_in,
                              void* d_out, int out_size, void* d_ws, size_t ws_size,
                              hipStream_t stream) {
  const float* x        = (const float*)d_in[0];
  const int*   edge_src = (const int*)d_in[1];
  const int*   edge_dst = (const int*)d_in[2];
  const float* edge_w   = (const float*)d_in[3];
  const float* weight   = (const float*)d_in[4];
  const float* bias     = (const float*)d_in[5];
  float* out = (float*)d_out;

  char* ws = (char*)d_ws;
  size_t off = 0;
  auto alloc = [&](size_t bytes) -> void* {
    void* p = ws + off;
    off = (off + bytes + 255) & ~(size_t)255;
    return p;
  };

  unsigned short* wt  = (unsigned short*)alloc(256 * 256 * 2);
  unsigned short* sup = (unsigned short*)alloc((size_t)M_PAD * 256 * 2);             // 51.25 MB
  unsigned long long* region = (unsigned long long*)alloc((size_t)NBKT * BCAP * 8);  // 28.84 MB
  int* gcur = (int*)alloc(NBKT * 4);

  convw_kernel<<<256, 256, 0, stream>>>(weight, wt, gcur);
  gemm_binA_kernel<<<NB_BINA + NB_GEMM, 256, 0, stream>>>(x, wt, sup,
                                                          edge_src, edge_dst, edge_w,
                                                          gcur, region);
  csr_gather_kernel<<<dim3(NBKT, 2), 256, 0, stream>>>(region, gcur, sup, bias, out);
}

// Round 6
// 492.418 us; speedup vs baseline: 1.0910x; 1.0055x over previous
//
#include <hip/hip_runtime.h>
#include <hip/hip_bf16.h>

#define N_NODES 100000
#define N_EDGES 3200000
#define DDIM    256
#define M_PAD   100096   // 782 * 128
#define NBKT    782      // buckets = dst >> 7 (128 dsts per bucket)
#define BCAP    4608     // mean 4096 + 8 sigma
#define EPB     4096     // edges per binA block
#define NB_BINA 782      // ceil(3.2M / 4096)
#define NB_GEMM 1564     // 782 * 2
#define GCAP    2432     // half-bucket capacity: mean 2048 + 8.5 sigma
#define SMEM_BYTES 50432 // union: binA 50344 | gemm dbuf 33280 / epi 34816

// quad-blocked LDS tile: [4 kquads][128 rows][8 ushorts], quad stride 1040 ushorts
#define QS 1040

typedef __attribute__((ext_vector_type(8))) short short8;
typedef __attribute__((ext_vector_type(4))) float f32x4;

typedef const __attribute__((address_space(1))) void gvoid_t;
typedef __attribute__((address_space(3))) void lvoid_t;

__device__ __forceinline__ unsigned short f2bf(float f) {
  __hip_bfloat16 h = __float2bfloat16(f);
  return *(unsigned short*)&h;
}
__device__ __forceinline__ float bflo(unsigned u) { return __uint_as_float(u << 16); }
__device__ __forceinline__ float bfhi(unsigned u) { return __uint_as_float(u & 0xffff0000u); }

// ---- dispatch 1: conv_w (fp32 [K][N] -> bf16 transposed [N][K]) + gcur init ----
__global__ void convw_kernel(const float* __restrict__ w, unsigned short* __restrict__ wt,
                             int* __restrict__ gcur) {
  int t = blockIdx.x * blockDim.x + threadIdx.x;   // 65536 threads
  int n = t >> 8, k = t & 255;
  wt[t] = f2bf(w[k * 256 + n]);                    // wt[n*256 + k]
  if (t < NBKT) gcur[t] = 0;
}

// ---- dispatch 2: fused binA + reg-staged pipelined MFMA GEMM ----
// GEMM rebuild (this round's experiment):
//  * A AND B reg-staged, 2-deep pipeline: loads for step k+1 issued BEFORE
//    COMPUTE(k); LDS writes after; ONE barrier/step; no global_load_lds ->
//    no vmcnt(0) barrier-drain of prefetches (T14).
//  * quad-blocked LDS [kquad][row][8] (quad stride 2080 B): uniform bank
//    spread on ds_write and ds_read_b128.
//  * epilogue: C -> bf16 LDS [128][136] -> coalesced dwordx4 stores
//    (replaces 64 scalar 2-byte scattered global stores per thread).
__global__ __launch_bounds__(256, 3) void gemm_binA_kernel(
    const float* __restrict__ x, const unsigned short* __restrict__ wt,
    unsigned short* __restrict__ sup,
    const int* __restrict__ src, const int* __restrict__ dst,
    const float* __restrict__ wgt,
    int* __restrict__ gcur, unsigned long long* __restrict__ region) {
  __shared__ __align__(16) char smem[SMEM_BYTES];
  const int bid = blockIdx.x;
  const int t = threadIdx.x;

  if (bid >= NB_BINA) {
    // ================= GEMM: sup = bf16(x) @ wt^T =================
    unsigned short* As0 = (unsigned short*)smem;              // 8320 B each
    unsigned short* Bs0 = (unsigned short*)(smem + 8320);
    unsigned short* As1 = (unsigned short*)(smem + 16640);
    unsigned short* Bs1 = (unsigned short*)(smem + 24960);    // end 33280
    const int g  = bid - NB_BINA;
    const int m0 = (g >> 1) * 128;
    const int n0 = (g & 1) * 128;
    const int w    = t >> 6;
    const int lane = t & 63;
    const int quad = lane >> 4;
    const int l15  = lane & 15;
    const int wr   = w >> 1, wc = w & 1;

    f32x4 acc[4][4] = {};

    // A: thread t, iter j: row = j*32 + (t>>3), k-chunk c = t&7 (4 floats)
    // LDS slot: quad q = c>>1, half h = c&1 -> ushort idx q*QS + row*8 + h*4
#define A_LOADG(kt, va)                                                       \
    do { _Pragma("unroll")                                                    \
      for (int j = 0; j < 4; ++j) {                                           \
        int row = j * 32 + (t >> 3);                                          \
        int xr = m0 + row; if (xr >= N_NODES) xr = N_NODES - 1;               \
        va[j] = *(const float4*)(x + (size_t)xr * 256 + (kt) + (t & 7) * 4);  \
      } } while (0)
#define A_STOREL(va, asb)                                                     \
    do { _Pragma("unroll")                                                    \
      for (int j = 0; j < 4; ++j) {                                           \
        int row = j * 32 + (t >> 3);                                          \
        int c = t & 7;                                                        \
        ushort4 o;                                                            \
        o.x = f2bf(va[j].x); o.y = f2bf(va[j].y);                             \
        o.z = f2bf(va[j].z); o.w = f2bf(va[j].w);                             \
        *(ushort4*)((asb) + (c >> 1) * QS + row * 8 + (c & 1) * 4) = o;       \
      } } while (0)
    // B: thread t, iter j: f = j*256+t; row = f>>2, kquad c2 = f&3 (8 ushorts)
#define B_LOADG(kt, vb)                                                       \
    do { _Pragma("unroll")                                                    \
      for (int j = 0; j < 2; ++j) {                                           \
        int f = j * 256 + t;                                                  \
        int row = f >> 2, c2 = f & 3;                                         \
        vb[j] = *(const short8*)(wt + (size_t)(n0 + row) * 256 + (kt) + c2 * 8); \
      } } while (0)
#define B_STOREL(vb, bsb)                                                     \
    do { _Pragma("unroll")                                                    \
      for (int j = 0; j < 2; ++j) {                                           \
        int f = j * 256 + t;                                                  \
        int row = f >> 2, c2 = f & 3;                                         \
        *(short8*)((bsb) + c2 * QS + row * 8) = vb[j];                        \
      } } while (0)
#define COMPUTE(asb, bsb)                                                     \
    do {                                                                      \
      short8 a[4], b[4];                                                      \
      _Pragma("unroll")                                                       \
      for (int mi = 0; mi < 4; ++mi)                                          \
        a[mi] = *(const short8*)((asb) + quad * QS + (wr * 64 + mi * 16 + l15) * 8); \
      _Pragma("unroll")                                                       \
      for (int ni = 0; ni < 4; ++ni)                                          \
        b[ni] = *(const short8*)((bsb) + quad * QS + (wc * 64 + ni * 16 + l15) * 8); \
      _Pragma("unroll")                                                       \
      for (int mi = 0; mi < 4; ++mi)                                          \
        _Pragma("unroll")                                                     \
        for (int ni = 0; ni < 4; ++ni)                                        \
          acc[mi][ni] = __builtin_amdgcn_mfma_f32_16x16x32_bf16(a[mi], b[ni], acc[mi][ni], 0, 0, 0); \
    } while (0)

    {
      float4 va[4]; short8 vb[2];
      A_LOADG(0, va); B_LOADG(0, vb);
      A_STOREL(va, As0); B_STOREL(vb, Bs0);
    }
    __syncthreads();
#pragma unroll
    for (int kp = 0; kp < 8; ++kp) {
      unsigned short* Ac = (kp & 1) ? As1 : As0;
      unsigned short* Bc = (kp & 1) ? Bs1 : Bs0;
      unsigned short* An = (kp & 1) ? As0 : As1;
      unsigned short* Bn = (kp & 1) ? Bs0 : Bs1;
      float4 va[4]; short8 vb[2];
      if (kp < 7) { A_LOADG((kp + 1) * 32, va); B_LOADG((kp + 1) * 32, vb); }
      COMPUTE(Ac, Bc);
      if (kp < 7) { A_STOREL(va, An); B_STOREL(vb, Bn); }
      __syncthreads();
    }

    // epilogue: stage C-tile bf16 in LDS [128][136], then coalesced stores
    unsigned short* Cs = (unsigned short*)smem;   // 128*136*2 = 34816 B
#pragma unroll
    for (int mi = 0; mi < 4; ++mi)
#pragma unroll
      for (int ni = 0; ni < 4; ++ni)
#pragma unroll
        for (int r = 0; r < 4; ++r)
          Cs[(wr * 64 + mi * 16 + quad * 4 + r) * 136 + wc * 64 + ni * 16 + l15] =
              f2bf(acc[mi][ni][r]);
    __syncthreads();
#pragma unroll
    for (int i = 0; i < 8; ++i) {
      int ch = i * 256 + t;              // 2048 chunks of 8 ushorts
      int r = ch >> 4, cc = (ch & 15) * 8;
      short8 v = *(const short8*)(Cs + r * 136 + cc);
      *(short8*)(sup + (size_t)(m0 + r) * 256 + n0 + cc) = v;
    }
    return;
  }

  // ================= binA: bin edges into bucket regions (unchanged) =====
  // pack: [w:32][dstlow:7 @bit17][src:17]
  unsigned long long* staged = (unsigned long long*)smem;        // [0, 32768)
  unsigned short* sbkt = (unsigned short*)(smem + 32768);        // [32768, 40960)
  int* lstart = (int*)(smem + 40960);                            // 782*4
  int* lcur   = (int*)(smem + 44088);
  int* gb     = (int*)(smem + 47216);                            // ends 50344
  int* lhist  = (int*)smem;                                      // alias: [0, 3128)
  int* csum   = (int*)(smem + 3200);                             // alias: [3200, 4224)

  const int e0 = bid * EPB;
  const int ecnt = min(EPB, N_EDGES - e0);

  for (int i = t; i < NBKT; i += 256) lhist[i] = 0;
  __syncthreads();
  for (int k = t; k < ecnt; k += 256)
    atomicAdd(&lhist[dst[e0 + k] >> 7], 1);
  __syncthreads();

  int i0 = 4 * t;
  int a0 = (i0 + 0 < NBKT) ? lhist[i0 + 0] : 0;
  int a1 = (i0 + 1 < NBKT) ? lhist[i0 + 1] : 0;
  int a2 = (i0 + 2 < NBKT) ? lhist[i0 + 2] : 0;
  int a3 = (i0 + 3 < NBKT) ? lhist[i0 + 3] : 0;
  int s = a0 + a1 + a2 + a3;
  csum[t] = s;
  __syncthreads();
  for (int off = 1; off < 256; off <<= 1) {
    int v = (t >= off) ? csum[t - off] : 0;
    __syncthreads();
    csum[t] += v;
    __syncthreads();
  }
  int base = csum[t] - s;
  if (i0 + 0 < NBKT) lstart[i0 + 0] = base; base += a0;
  if (i0 + 1 < NBKT) lstart[i0 + 1] = base; base += a1;
  if (i0 + 2 < NBKT) lstart[i0 + 2] = base; base += a2;
  if (i0 + 3 < NBKT) lstart[i0 + 3] = base;
  __syncthreads();

  for (int i = t; i < NBKT; i += 256) {
    int c = lhist[i];
    int off = c ? atomicAdd(&gcur[i], c) : 0;
    gb[i] = i * BCAP + off;
    lcur[i] = lstart[i];
  }
  __syncthreads();   // lhist/csum dead past here; staged may now be written

  for (int k = t; k < ecnt; k += 256) {
    int d  = dst[e0 + k];
    int sr = src[e0 + k];
    float wv = wgt[e0 + k];
    int b = d >> 7;
    int p = atomicAdd(&lcur[b], 1);
    staged[p] = ((unsigned long long)__float_as_uint(wv) << 32) |
                ((unsigned)(d & 127) << 17) | (unsigned)sr;
    sbkt[p] = (unsigned short)b;
  }
  __syncthreads();

  for (int j = t; j < ecnt; j += 256) {
    int b = sbkt[j];
    int addr = gb[b] + (j - lstart[b]);
    if (addr < (b + 1) * BCAP) region[addr] = staged[j];  // overflow guard (never fires)
  }
}

// ---- dispatch 3: fused sort + gather, row-split (UNCHANGED — control) ----
__global__ __launch_bounds__(256) void csr_gather_kernel(
    const unsigned long long* __restrict__ region,
    const int* __restrict__ gcur,
    const unsigned short* __restrict__ sup,
    const float* __restrict__ bias,
    float* __restrict__ out) {
  __shared__ unsigned long long lcsr[GCAP];
  __shared__ int lhist[64], loff[64], lcur[64];
  const int t = threadIdx.x;
  const int b = blockIdx.x;
  const int h = blockIdx.y;          // half: dsts [h*64, h*64+64)
  const int cnt = min(gcur[b], BCAP);
  const int base = b * BCAP;

  if (t < 64) lhist[t] = 0;
  __syncthreads();
  for (int j = t; j < cnt; j += 256) {
    unsigned lo = (unsigned)(region[base + j] & 0xffffffffu);
    int dl = (int)((lo >> 17) & 127);
    if ((dl >> 6) == h) atomicAdd(&lhist[dl & 63], 1);
  }
  __syncthreads();
  if (t < 64) loff[t] = lhist[t];
  __syncthreads();
  for (int off = 1; off < 64; off <<= 1) {
    int v = (t >= off && t < 64) ? loff[t - off] : 0;
    __syncthreads();
    if (t < 64) loff[t] += v;
    __syncthreads();
  }
  if (t < 64) { loff[t] -= lhist[t]; lcur[t] = loff[t]; }
  __syncthreads();
  for (int j = t; j < cnt; j += 256) {
    unsigned long long e = region[base + j];
    int dl = (int)((e >> 17) & 127);
    if ((dl >> 6) == h) {
      int p = atomicAdd(&lcur[dl & 63], 1);
      if (p < GCAP) lcsr[p] = e;   // overflow guard (never fires)
    }
  }
  __syncthreads();

  const int wv = t >> 6;
  const int c0 = (t & 63) * 4;
  float4 bv = *(const float4*)(bias + c0);

  for (int dl = wv; dl < 64; dl += 4) {
    int node = b * 128 + h * 64 + dl;
    if (node >= N_NODES) continue;   // wave-uniform
    int start = loff[dl];
    int end   = min(lcur[dl], GCAP);
    float a0 = bv.x, a1 = bv.y, a2 = bv.z, a3 = bv.w;

    int i = start;
    for (; i + 2 <= end; i += 2) {
      unsigned long long m0 = lcsr[i];
      unsigned long long m1 = lcsr[i + 1];
      int   s0 = (int)(m0 & 0x1ffffu);
      float w0 = __uint_as_float((unsigned)(m0 >> 32));
      int   s1 = (int)(m1 & 0x1ffffu);
      float w1 = __uint_as_float((unsigned)(m1 >> 32));
      uint2 p0 = *(const uint2*)(sup + (size_t)s0 * 256 + c0);
      uint2 p1 = *(const uint2*)(sup + (size_t)s1 * 256 + c0);
      a0 = fmaf(w0, bflo(p0.x), a0);
      a1 = fmaf(w0, bfhi(p0.x), a1);
      a2 = fmaf(w0, bflo(p0.y), a2);
      a3 = fmaf(w0, bfhi(p0.y), a3);
      a0 = fmaf(w1, bflo(p1.x), a0);
      a1 = fmaf(w1, bfhi(p1.x), a1);
      a2 = fmaf(w1, bflo(p1.y), a2);
      a3 = fmaf(w1, bfhi(p1.y), a3);
    }
    if (i < end) {
      unsigned long long m0 = lcsr[i];
      int   s0 = (int)(m0 & 0x1ffffu);
      float w0 = __uint_as_float((unsigned)(m0 >> 32));
      uint2 p0 = *(const uint2*)(sup + (size_t)s0 * 256 + c0);
      a0 = fmaf(w0, bflo(p0.x), a0);
      a1 = fmaf(w0, bfhi(p0.x), a1);
      a2 = fmaf(w0, bflo(p0.y), a2);
      a3 = fmaf(w0, bfhi(p0.y), a3);
    }
    *(float4*)(out + (size_t)node * 256 + c0) = make_float4(a0, a1, a2, a3);
  }
}

extern "C" void kernel_launch(void* const* d_in, const int* in_sizes, int n_in,
                              void* d_out, int out_size, void* d_ws, size_t ws_size,
                              hipStream_t stream) {
  const float* x        = (const float*)d_in[0];
  const int*   edge_src = (const int*)d_in[1];
  const int*   edge_dst = (const int*)d_in[2];
  const float* edge_w   = (const float*)d_in[3];
  const float* weight   = (const float*)d_in[4];
  const float* bias     = (const float*)d_in[5];
  float* out = (float*)d_out;

  char* ws = (char*)d_ws;
  size_t off = 0;
  auto alloc = [&](size_t bytes) -> void* {
    void* p = ws + off;
    off = (off + bytes + 255) & ~(size_t)255;
    return p;
  };

  unsigned short* wt  = (unsigned short*)alloc(256 * 256 * 2);
  unsigned short* sup = (unsigned short*)alloc((size_t)M_PAD * 256 * 2);             // 51.25 MB
  unsigned long long* region = (unsigned long long*)alloc((size_t)NBKT * BCAP * 8);  // 28.84 MB
  int* gcur = (int*)alloc(NBKT * 4);

  convw_kernel<<<256, 256, 0, stream>>>(weight, wt, gcur);
  gemm_binA_kernel<<<NB_BINA + NB_GEMM, 256, 0, stream>>>(x, wt, sup,
                                                          edge_src, edge_dst, edge_w,
                                                          gcur, region);
  csr_gather_kernel<<<dim3(NBKT, 2), 256, 0, stream>>>(region, gcur, sup, bias, out);
}